// Round 1
// baseline (14514.351 us; speedup 1.0000x reference)
//
#include <hip/hip_runtime.h>

// ---------------------------------------------------------------------------
// GCN 3-layer forward on MI355X.
// Math: out = A_n relu(A_n relu(A_n x W1^T) W2^T) W3^T with
//   A_n = D^-1/2 (A + I) D^-1/2, deg computed over col (targets) + self loop.
// We use the commuted form: gcn_conv(h,W) = (A_n h) W^T  (aggregation first),
// which (a) halves layer-1 scatter width (128 vs 256), (b) fuses ReLU into
// the GEMM epilogue, (c) fuses the self-loop term into buffer init.
// ---------------------------------------------------------------------------

constexpr int DIN = 128;
constexpr int DH  = 256;

__global__ void zero_int_kernel(int* __restrict__ p, int n) {
    int i = blockIdx.x * blockDim.x + threadIdx.x;
    if (i < n) p[i] = 0;
}

__global__ void count_deg_kernel(const int* __restrict__ col, int E, int* __restrict__ deg) {
    int e = blockIdx.x * blockDim.x + threadIdx.x;
    if (e < E) atomicAdd(&deg[col[e]], 1);
}

__global__ void dinv_kernel(const int* __restrict__ deg, float* __restrict__ dinv, int N) {
    int n = blockIdx.x * blockDim.x + threadIdx.x;
    if (n < N) {
        float d = (float)(deg[n] + 1);   // +1 self-loop; always >= 1
        dinv[n] = 1.0f / sqrtf(d);
    }
}

// out[n][:] = dinv[n]^2 * in[n][:]   (self-loop contribution; also zero-init)
template<int D>
__global__ void self_init_kernel(const float4* __restrict__ in, const float* __restrict__ dinv,
                                 float4* __restrict__ out, int N) {
    constexpr int L = D / 4;
    int i = blockIdx.x * blockDim.x + threadIdx.x;
    if (i >= N * L) return;
    int n = i / L;                      // L is power of 2 -> shift
    float di = dinv[n];
    float s = di * di;
    float4 v = in[i];
    out[i] = make_float4(v.x * s, v.y * s, v.z * s, v.w * s);
}

// One edge per (D/4)-lane group; float4 per lane; scatter via f32 atomics.
template<int D>
__global__ void agg_edges_kernel(const int* __restrict__ row, const int* __restrict__ col,
                                 const float* __restrict__ dinv,
                                 const float4* __restrict__ in, float* __restrict__ out,
                                 int E) {
    constexpr int L = D / 4;            // lanes per edge (32 or 64)
    constexpr int EPB = 256 / L;        // edges per 256-thread block
    int e = blockIdx.x * EPB + threadIdx.x / L;
    if (e >= E) return;
    int lane = threadIdx.x % L;
    int r = row[e];
    int c = col[e];
    float norm = dinv[r] * dinv[c];
    float4 v = in[(size_t)r * L + lane];
    float* op = out + (size_t)c * D + (size_t)lane * 4;
    atomicAdd(op + 0, v.x * norm);
    atomicAdd(op + 1, v.y * norm);
    atomicAdd(op + 2, v.z * norm);
    atomicAdd(op + 3, v.w * norm);
}

// C[n][m] = sum_k A[n][k] * W[m][k]   (A:[N,K] row-major, W:[256,K] row-major)
// 64x64 tile, 256 threads, 4x4 acc/thread, K tiled by 32, float4 LDS reads.
template<int K, bool RELU>
__global__ __launch_bounds__(256) void gemm_nt_kernel(const float* __restrict__ A,
                                                      const float* __restrict__ W,
                                                      float* __restrict__ C, int N) {
    __shared__ __align__(16) float As[64][36];   // pad 36: float4-aligned rows, 2-way LDS max
    __shared__ __align__(16) float Bs[64][36];
    int tid = threadIdx.x;
    int tx = tid & 15, ty = tid >> 4;
    int m0 = blockIdx.x * 64;
    int n0 = blockIdx.y * 64;
    float acc[4][4] = {};

    for (int k0 = 0; k0 < K; k0 += 32) {
        #pragma unroll
        for (int p = tid; p < 512; p += 256) {
            int rr = p >> 3, c4 = p & 7;
            int gr = m0 + rr;
            float4 va = make_float4(0.f, 0.f, 0.f, 0.f);
            if (gr < N) va = *(const float4*)(A + (size_t)gr * K + k0 + c4 * 4);
            *(float4*)&As[rr][c4 * 4] = va;
            float4 vb = *(const float4*)(W + (size_t)(n0 + rr) * K + k0 + c4 * 4);
            *(float4*)&Bs[rr][c4 * 4] = vb;
        }
        __syncthreads();
        #pragma unroll
        for (int kk = 0; kk < 32; kk += 4) {
            float4 a[4], b[4];
            #pragma unroll
            for (int i = 0; i < 4; i++) a[i] = *(const float4*)&As[ty * 4 + i][kk];
            #pragma unroll
            for (int j = 0; j < 4; j++) b[j] = *(const float4*)&Bs[tx * 4 + j][kk];
            #pragma unroll
            for (int i = 0; i < 4; i++)
                #pragma unroll
                for (int j = 0; j < 4; j++)
                    acc[i][j] += a[i].x * b[j].x + a[i].y * b[j].y +
                                 a[i].z * b[j].z + a[i].w * b[j].w;
        }
        __syncthreads();
    }

    #pragma unroll
    for (int i = 0; i < 4; i++) {
        int r = m0 + ty * 4 + i;
        if (r >= N) break;
        float4 v = make_float4(acc[i][0], acc[i][1], acc[i][2], acc[i][3]);
        if (RELU) {
            v.x = fmaxf(v.x, 0.f); v.y = fmaxf(v.y, 0.f);
            v.z = fmaxf(v.z, 0.f); v.w = fmaxf(v.w, 0.f);
        }
        *(float4*)(C + (size_t)r * DH + n0 + tx * 4) = v;
    }
}

extern "C" void kernel_launch(void* const* d_in, const int* in_sizes, int n_in,
                              void* d_out, int out_size, void* d_ws, size_t ws_size,
                              hipStream_t stream) {
    const float* x  = (const float*)d_in[0];
    const int*   ei = (const int*)d_in[1];
    const float* W1 = (const float*)d_in[2];
    const float* W2 = (const float*)d_in[3];
    const float* W3 = (const float*)d_in[4];
    float* out = (float*)d_out;

    int N = in_sizes[0] / DIN;
    int E = in_sizes[1] / 2;
    const int* row = ei;         // sources
    const int* col = ei + E;     // targets (aggregation)

    char* ws = (char*)d_ws;
    int*   deg  = (int*)ws;                    // N ints
    float* dinv = (float*)(ws + 400000);       // N floats
    float* bufS = (float*)(ws + 800000);       // N*256 floats (16B aligned: 800000%16==0)

    dim3 b256(256);

    // degree + dinv
    zero_int_kernel<<<dim3((N + 255) / 256), b256, 0, stream>>>(deg, N);
    count_deg_kernel<<<dim3((E + 255) / 256), b256, 0, stream>>>(col, E, deg);
    dinv_kernel<<<dim3((N + 255) / 256), b256, 0, stream>>>(deg, dinv, N);

    // ---- Layer 1: s = A_n x (128-wide), h1 = relu(s @ W1^T) -> d_out
    self_init_kernel<DIN><<<dim3((N * (DIN / 4) + 255) / 256), b256, 0, stream>>>(
        (const float4*)x, dinv, (float4*)bufS, N);
    agg_edges_kernel<DIN><<<dim3((E + 7) / 8), b256, 0, stream>>>(
        row, col, dinv, (const float4*)x, bufS, E);
    gemm_nt_kernel<DIN, true><<<dim3((N + 63) / 64, DH / 64), b256, 0, stream>>>(
        bufS, W1, out, N);

    // ---- Layer 2: s = A_n h1, h2 = relu(s @ W2^T) -> d_out
    self_init_kernel<DH><<<dim3((N * (DH / 4) + 255) / 256), b256, 0, stream>>>(
        (const float4*)out, dinv, (float4*)bufS, N);
    agg_edges_kernel<DH><<<dim3((E + 3) / 4), b256, 0, stream>>>(
        row, col, dinv, (const float4*)out, bufS, E);
    gemm_nt_kernel<DH, true><<<dim3((N + 63) / 64, DH / 64), b256, 0, stream>>>(
        bufS, W2, out, N);

    // ---- Layer 3: s = A_n h2, out = s @ W3^T (no relu) -> d_out
    self_init_kernel<DH><<<dim3((N * (DH / 4) + 255) / 256), b256, 0, stream>>>(
        (const float4*)out, dinv, (float4*)bufS, N);
    agg_edges_kernel<DH><<<dim3((E + 3) / 4), b256, 0, stream>>>(
        row, col, dinv, (const float4*)out, bufS, E);
    gemm_nt_kernel<DH, false><<<dim3((N + 63) / 64, DH / 64), b256, 0, stream>>>(
        bufS, W3, out, N);
}

// Round 2
// 1825.992 us; speedup vs baseline: 7.9487x; 7.9487x over previous
//
#include <hip/hip_runtime.h>

// ---------------------------------------------------------------------------
// GCN 3-layer forward on MI355X — Round 2: CSR gather instead of atomic scatter.
// gcn_conv(h,W) = (A_n h) W^T (aggregation commuted before the transform).
// Aggregation: build CSR by target node (per call; d_ws is re-poisoned), then
// one wave-group per node gathers neighbor rows (coalesced 1KB reads, mostly
// L3 hits) and writes its output row once. Self-loop term fused into acc init.
// ---------------------------------------------------------------------------

constexpr int DIN = 128;
constexpr int DH  = 256;

__global__ void zero_int_kernel(int* __restrict__ p, int n) {
    int i = blockIdx.x * blockDim.x + threadIdx.x;
    if (i < n) p[i] = 0;
}

__global__ void count_deg_kernel(const int* __restrict__ col, int E, int* __restrict__ deg) {
    int e = blockIdx.x * blockDim.x + threadIdx.x;
    if (e < E) atomicAdd(&deg[col[e]], 1);
}

// Single-block exclusive scan: deg[0..N) -> rowptr[0..N], rowptr[N] = E.
__global__ __launch_bounds__(1024) void scan_kernel(const int* __restrict__ deg,
                                                    int* __restrict__ rowptr, int N) {
    __shared__ int sums[1024];
    int t = threadIdx.x;
    int chunk = (N + 1023) / 1024;
    int s0 = t * chunk, s1 = min(N, s0 + chunk);
    int local = 0;
    for (int i = s0; i < s1; i++) local += deg[i];
    sums[t] = local;
    __syncthreads();
    for (int off = 1; off < 1024; off <<= 1) {
        int v = (t >= off) ? sums[t - off] : 0;
        __syncthreads();
        sums[t] += v;
        __syncthreads();
    }
    int prefix = (t == 0) ? 0 : sums[t - 1];
    for (int i = s0; i < s1; i++) { rowptr[i] = prefix; prefix += deg[i]; }
    if (t == 1023) rowptr[N] = sums[1023];
}

// dinv = 1/sqrt(deg+1); also zero deg for reuse as the CSR fill cursor.
__global__ void dinv_kernel(int* __restrict__ deg, float* __restrict__ dinv, int N) {
    int n = blockIdx.x * blockDim.x + threadIdx.x;
    if (n < N) {
        float d = (float)(deg[n] + 1);
        dinv[n] = 1.0f / sqrtf(d);
        deg[n] = 0;
    }
}

__global__ void fill_csr_kernel(const int* __restrict__ row, const int* __restrict__ col,
                                const int* __restrict__ rowptr, int* __restrict__ cnt,
                                const float* __restrict__ dinv,
                                int* __restrict__ csr_src, float* __restrict__ csr_w, int E) {
    int e = blockIdx.x * blockDim.x + threadIdx.x;
    if (e >= E) return;
    int r = row[e], c = col[e];
    int pos = rowptr[c] + atomicAdd(&cnt[c], 1);
    csr_src[pos] = r;
    csr_w[pos]   = dinv[r] * dinv[c];
}

// One L-lane group per node (L = D/4 lanes, float4 each). Gather + accumulate.
template<int D>
__global__ __launch_bounds__(256) void agg_gather_kernel(const int* __restrict__ rowptr,
                                                         const int* __restrict__ csr_src,
                                                         const float* __restrict__ csr_w,
                                                         const float* __restrict__ dinv,
                                                         const float4* __restrict__ in,
                                                         float4* __restrict__ out, int N) {
    constexpr int L = D / 4;                 // 32 or 64 lanes per node
    constexpr int GPB = 256 / L;             // node groups per block
    int n = blockIdx.x * GPB + threadIdx.x / L;
    if (n >= N) return;
    int lane = threadIdx.x % L;

    float di = dinv[n];
    float s = di * di;
    float4 acc = in[(size_t)n * L + lane];   // self-loop term
    acc.x *= s; acc.y *= s; acc.z *= s; acc.w *= s;

    int start = rowptr[n], end = rowptr[n + 1];
    for (int j0 = start; j0 < end; j0 += L) {
        int nb = end - j0; if (nb > L) nb = L;
        int   src = 0;
        float w   = 0.0f;
        if (lane < nb) { src = csr_src[j0 + lane]; w = csr_w[j0 + lane]; }
        for (int t = 0; t < nb; ++t) {
            int   r  = __shfl(src, t, L);
            float ww = __shfl(w,   t, L);
            float4 v = in[(size_t)r * L + lane];
            acc.x += ww * v.x; acc.y += ww * v.y;
            acc.z += ww * v.z; acc.w += ww * v.w;
        }
    }
    out[(size_t)n * L + lane] = acc;
}

// C[n][m] = sum_k A[n][k] * W[m][k]; 64x64 tile, 4x4 acc/thread, fused ReLU.
template<int K, bool RELU>
__global__ __launch_bounds__(256) void gemm_nt_kernel(const float* __restrict__ A,
                                                      const float* __restrict__ W,
                                                      float* __restrict__ C, int N) {
    __shared__ __align__(16) float As[64][36];
    __shared__ __align__(16) float Bs[64][36];
    int tid = threadIdx.x;
    int tx = tid & 15, ty = tid >> 4;
    int m0 = blockIdx.x * 64;
    int n0 = blockIdx.y * 64;
    float acc[4][4] = {};

    for (int k0 = 0; k0 < K; k0 += 32) {
        #pragma unroll
        for (int p = tid; p < 512; p += 256) {
            int rr = p >> 3, c4 = p & 7;
            int gr = m0 + rr;
            float4 va = make_float4(0.f, 0.f, 0.f, 0.f);
            if (gr < N) va = *(const float4*)(A + (size_t)gr * K + k0 + c4 * 4);
            *(float4*)&As[rr][c4 * 4] = va;
            float4 vb = *(const float4*)(W + (size_t)(n0 + rr) * K + k0 + c4 * 4);
            *(float4*)&Bs[rr][c4 * 4] = vb;
        }
        __syncthreads();
        #pragma unroll
        for (int kk = 0; kk < 32; kk += 4) {
            float4 a[4], b[4];
            #pragma unroll
            for (int i = 0; i < 4; i++) a[i] = *(const float4*)&As[ty * 4 + i][kk];
            #pragma unroll
            for (int j = 0; j < 4; j++) b[j] = *(const float4*)&Bs[tx * 4 + j][kk];
            #pragma unroll
            for (int i = 0; i < 4; i++)
                #pragma unroll
                for (int j = 0; j < 4; j++)
                    acc[i][j] += a[i].x * b[j].x + a[i].y * b[j].y +
                                 a[i].z * b[j].z + a[i].w * b[j].w;
        }
        __syncthreads();
    }

    #pragma unroll
    for (int i = 0; i < 4; i++) {
        int r = m0 + ty * 4 + i;
        if (r >= N) break;
        float4 v = make_float4(acc[i][0], acc[i][1], acc[i][2], acc[i][3]);
        if (RELU) {
            v.x = fmaxf(v.x, 0.f); v.y = fmaxf(v.y, 0.f);
            v.z = fmaxf(v.z, 0.f); v.w = fmaxf(v.w, 0.f);
        }
        *(float4*)(C + (size_t)r * DH + n0 + tx * 4) = v;
    }
}

extern "C" void kernel_launch(void* const* d_in, const int* in_sizes, int n_in,
                              void* d_out, int out_size, void* d_ws, size_t ws_size,
                              hipStream_t stream) {
    const float* x  = (const float*)d_in[0];
    const int*   ei = (const int*)d_in[1];
    const float* W1 = (const float*)d_in[2];
    const float* W2 = (const float*)d_in[3];
    const float* W3 = (const float*)d_in[4];
    float* out = (float*)d_out;

    int N = in_sizes[0] / DIN;
    int E = in_sizes[1] / 2;
    const int* row = ei;         // sources
    const int* col = ei + E;     // targets (aggregation)

    char* ws = (char*)d_ws;
    int*   deg     = (int*)ws;                      // N ints (later: fill cursor)
    float* dinv    = (float*)(ws + 400000);         // N floats
    int*   rowptr  = (int*)(ws + 800000);           // N+1 ints
    int*   csr_src = (int*)(ws + 1200016);          // E ints
    float* csr_w   = (float*)(ws + 7600016);        // E floats
    float* bufS    = (float*)(ws + 14000128);       // N*256 floats, 16B aligned

    dim3 b256(256);

    // CSR build: deg -> rowptr -> dinv (+cursor reset) -> fill
    zero_int_kernel<<<dim3((N + 255) / 256), b256, 0, stream>>>(deg, N);
    count_deg_kernel<<<dim3((E + 255) / 256), b256, 0, stream>>>(col, E, deg);
    scan_kernel<<<dim3(1), dim3(1024), 0, stream>>>(deg, rowptr, N);
    dinv_kernel<<<dim3((N + 255) / 256), b256, 0, stream>>>(deg, dinv, N);
    fill_csr_kernel<<<dim3((E + 255) / 256), b256, 0, stream>>>(
        row, col, rowptr, deg, dinv, csr_src, csr_w, E);

    // ---- Layer 1: s = A_n x (128-wide), h1 = relu(s @ W1^T) -> d_out
    agg_gather_kernel<DIN><<<dim3((N + 7) / 8), b256, 0, stream>>>(
        rowptr, csr_src, csr_w, dinv, (const float4*)x, (float4*)bufS, N);
    gemm_nt_kernel<DIN, true><<<dim3((N + 63) / 64, DH / 64), b256, 0, stream>>>(
        bufS, W1, out, N);

    // ---- Layer 2
    agg_gather_kernel<DH><<<dim3((N + 3) / 4), b256, 0, stream>>>(
        rowptr, csr_src, csr_w, dinv, (const float4*)out, (float4*)bufS, N);
    gemm_nt_kernel<DH, true><<<dim3((N + 63) / 64, DH / 64), b256, 0, stream>>>(
        bufS, W2, out, N);

    // ---- Layer 3 (no relu)
    agg_gather_kernel<DH><<<dim3((N + 3) / 4), b256, 0, stream>>>(
        rowptr, csr_src, csr_w, dinv, (const float4*)out, (float4*)bufS, N);
    gemm_nt_kernel<DH, false><<<dim3((N + 63) / 64, DH / 64), b256, 0, stream>>>(
        bufS, W3, out, N);
}

// Round 3
// 1528.860 us; speedup vs baseline: 9.4936x; 1.1943x over previous
//
#include <hip/hip_runtime.h>

// ---------------------------------------------------------------------------
// GCN 3-layer forward on MI355X — Round 3: conflict-free full-width GEMM.
// gcn_conv(h,W) = (A_n h) W^T (aggregation commuted before the transform).
// Aggregation: CSR gather (R2). GEMM: 64x256 output tile per block, A fetched
// once; As row-major scalar reads (2-way broadcast = free), W staged k-major
// for b128 fragment reads (2-way = free). R2's Bs reads were ~8-way conflicted
// (7.7e7 conflict cycles) and A was fetched 2x.
// ---------------------------------------------------------------------------

constexpr int DIN = 128;
constexpr int DH  = 256;

__global__ void zero_int_kernel(int* __restrict__ p, int n) {
    int i = blockIdx.x * blockDim.x + threadIdx.x;
    if (i < n) p[i] = 0;
}

__global__ void count_deg_kernel(const int* __restrict__ col, int E, int* __restrict__ deg) {
    int e = blockIdx.x * blockDim.x + threadIdx.x;
    if (e < E) atomicAdd(&deg[col[e]], 1);
}

// Single-block exclusive scan: deg[0..N) -> rowptr[0..N], rowptr[N] = E.
__global__ __launch_bounds__(1024) void scan_kernel(const int* __restrict__ deg,
                                                    int* __restrict__ rowptr, int N) {
    __shared__ int sums[1024];
    int t = threadIdx.x;
    int chunk = (N + 1023) / 1024;
    int s0 = t * chunk, s1 = min(N, s0 + chunk);
    int local = 0;
    for (int i = s0; i < s1; i++) local += deg[i];
    sums[t] = local;
    __syncthreads();
    for (int off = 1; off < 1024; off <<= 1) {
        int v = (t >= off) ? sums[t - off] : 0;
        __syncthreads();
        sums[t] += v;
        __syncthreads();
    }
    int prefix = (t == 0) ? 0 : sums[t - 1];
    for (int i = s0; i < s1; i++) { rowptr[i] = prefix; prefix += deg[i]; }
    if (t == 1023) rowptr[N] = sums[1023];
}

// dinv = 1/sqrt(deg+1); also zero deg for reuse as the CSR fill cursor.
__global__ void dinv_kernel(int* __restrict__ deg, float* __restrict__ dinv, int N) {
    int n = blockIdx.x * blockDim.x + threadIdx.x;
    if (n < N) {
        float d = (float)(deg[n] + 1);
        dinv[n] = 1.0f / sqrtf(d);
        deg[n] = 0;
    }
}

__global__ void fill_csr_kernel(const int* __restrict__ row, const int* __restrict__ col,
                                const int* __restrict__ rowptr, int* __restrict__ cnt,
                                const float* __restrict__ dinv,
                                int* __restrict__ csr_src, float* __restrict__ csr_w, int E) {
    int e = blockIdx.x * blockDim.x + threadIdx.x;
    if (e >= E) return;
    int r = row[e], c = col[e];
    int pos = rowptr[c] + atomicAdd(&cnt[c], 1);
    csr_src[pos] = r;
    csr_w[pos]   = dinv[r] * dinv[c];
}

// One L-lane group per node (L = D/4 lanes, float4 each). Gather + accumulate.
template<int D>
__global__ __launch_bounds__(256) void agg_gather_kernel(const int* __restrict__ rowptr,
                                                         const int* __restrict__ csr_src,
                                                         const float* __restrict__ csr_w,
                                                         const float* __restrict__ dinv,
                                                         const float4* __restrict__ in,
                                                         float4* __restrict__ out, int N) {
    constexpr int L = D / 4;                 // 32 or 64 lanes per node
    constexpr int GPB = 256 / L;             // node groups per block
    int n = blockIdx.x * GPB + threadIdx.x / L;
    if (n >= N) return;
    int lane = threadIdx.x % L;

    float di = dinv[n];
    float s = di * di;
    float4 acc = in[(size_t)n * L + lane];   // self-loop term
    acc.x *= s; acc.y *= s; acc.z *= s; acc.w *= s;

    int start = rowptr[n], end = rowptr[n + 1];
    for (int j0 = start; j0 < end; j0 += L) {
        int nb = end - j0; if (nb > L) nb = L;
        int   src = 0;
        float w   = 0.0f;
        if (lane < nb) { src = csr_src[j0 + lane]; w = csr_w[j0 + lane]; }
        for (int t = 0; t < nb; ++t) {
            int   r  = __shfl(src, t, L);
            float ww = __shfl(w,   t, L);
            float4 v = in[(size_t)r * L + lane];
            acc.x += ww * v.x; acc.y += ww * v.y;
            acc.z += ww * v.z; acc.w += ww * v.w;
        }
    }
    out[(size_t)n * L + lane] = acc;
}

// C[n][m] = sum_k A[n][k] * W[m][k];  A:[N,K] rm, W:[256,K] rm, C:[N,256] rm.
// 64x256 tile / block, 256 threads, 4 rows x 16 cols per thread.
// As: row-major [64][36]  -> scalar reads, 2-way broadcast (free).
// Ws: k-major  [32][260]  -> 4x ds_read_b128 per kk over 64 consecutive
//                            floats (inherent 2-way, free). Staged transposed.
template<int K, bool RELU>
__global__ __launch_bounds__(256) void gemm_nt_kernel(const float* __restrict__ A,
                                                      const float* __restrict__ W,
                                                      float* __restrict__ C, int N) {
    __shared__ __align__(16) float As[64][36];
    __shared__ __align__(16) float Ws[32][260];
    int tid = threadIdx.x;
    int tx = tid & 15, ty = tid >> 4;
    int m0 = blockIdx.x * 64;

    float4 acc[4][4];   // [row i][col block j], cols = tx*4 + 64*j .. +3
    #pragma unroll
    for (int i = 0; i < 4; i++)
        #pragma unroll
        for (int j = 0; j < 4; j++) acc[i][j] = make_float4(0.f, 0.f, 0.f, 0.f);

    for (int k0 = 0; k0 < K; k0 += 32) {
        // stage A tile: 64 rows x 32 k = 512 float4, 2 per thread
        #pragma unroll
        for (int p = tid; p < 512; p += 256) {
            int rr = p >> 3, c4 = p & 7;
            int gr = m0 + rr;
            float4 va = make_float4(0.f, 0.f, 0.f, 0.f);
            if (gr < N) va = *(const float4*)(A + (size_t)gr * K + k0 + c4 * 4);
            *(float4*)&As[rr][c4 * 4] = va;
        }
        // stage W tile transposed: 256 m x 32 k = 2048 float4, 8 per thread
        #pragma unroll
        for (int q = 0; q < 8; ++q) {
            int p = q * 256 + tid;
            int m = p >> 3, c4 = p & 7;
            float4 w = *(const float4*)(W + (size_t)m * K + k0 + c4 * 4);
            Ws[c4 * 4 + 0][m] = w.x;
            Ws[c4 * 4 + 1][m] = w.y;
            Ws[c4 * 4 + 2][m] = w.z;
            Ws[c4 * 4 + 3][m] = w.w;
        }
        __syncthreads();

        #pragma unroll 4
        for (int kk = 0; kk < 32; ++kk) {
            float a[4];
            #pragma unroll
            for (int i = 0; i < 4; i++) a[i] = As[ty * 4 + i][kk];
            float4 w[4];
            #pragma unroll
            for (int j = 0; j < 4; j++) w[j] = *(const float4*)&Ws[kk][tx * 4 + 64 * j];
            #pragma unroll
            for (int i = 0; i < 4; i++)
                #pragma unroll
                for (int j = 0; j < 4; j++) {
                    acc[i][j].x += a[i] * w[j].x;
                    acc[i][j].y += a[i] * w[j].y;
                    acc[i][j].z += a[i] * w[j].z;
                    acc[i][j].w += a[i] * w[j].w;
                }
        }
        __syncthreads();
    }

    #pragma unroll
    for (int i = 0; i < 4; i++) {
        int r = m0 + ty * 4 + i;
        if (r >= N) break;
        #pragma unroll
        for (int j = 0; j < 4; j++) {
            float4 v = acc[i][j];
            if (RELU) {
                v.x = fmaxf(v.x, 0.f); v.y = fmaxf(v.y, 0.f);
                v.z = fmaxf(v.z, 0.f); v.w = fmaxf(v.w, 0.f);
            }
            *(float4*)(C + (size_t)r * DH + tx * 4 + 64 * j) = v;
        }
    }
}

extern "C" void kernel_launch(void* const* d_in, const int* in_sizes, int n_in,
                              void* d_out, int out_size, void* d_ws, size_t ws_size,
                              hipStream_t stream) {
    const float* x  = (const float*)d_in[0];
    const int*   ei = (const int*)d_in[1];
    const float* W1 = (const float*)d_in[2];
    const float* W2 = (const float*)d_in[3];
    const float* W3 = (const float*)d_in[4];
    float* out = (float*)d_out;

    int N = in_sizes[0] / DIN;
    int E = in_sizes[1] / 2;
    const int* row = ei;         // sources
    const int* col = ei + E;     // targets (aggregation)

    char* ws = (char*)d_ws;
    int*   deg     = (int*)ws;                      // N ints (later: fill cursor)
    float* dinv    = (float*)(ws + 400000);         // N floats
    int*   rowptr  = (int*)(ws + 800000);           // N+1 ints
    int*   csr_src = (int*)(ws + 1200016);          // E ints
    float* csr_w   = (float*)(ws + 7600016);        // E floats
    float* bufS    = (float*)(ws + 14000128);       // N*256 floats, 16B aligned

    dim3 b256(256);

    // CSR build: deg -> rowptr -> dinv (+cursor reset) -> fill
    zero_int_kernel<<<dim3((N + 255) / 256), b256, 0, stream>>>(deg, N);
    count_deg_kernel<<<dim3((E + 255) / 256), b256, 0, stream>>>(col, E, deg);
    scan_kernel<<<dim3(1), dim3(1024), 0, stream>>>(deg, rowptr, N);
    dinv_kernel<<<dim3((N + 255) / 256), b256, 0, stream>>>(deg, dinv, N);
    fill_csr_kernel<<<dim3((E + 255) / 256), b256, 0, stream>>>(
        row, col, rowptr, deg, dinv, csr_src, csr_w, E);

    // ---- Layer 1: s = A_n x (128-wide), h1 = relu(s @ W1^T) -> d_out
    agg_gather_kernel<DIN><<<dim3((N + 7) / 8), b256, 0, stream>>>(
        rowptr, csr_src, csr_w, dinv, (const float4*)x, (float4*)bufS, N);
    gemm_nt_kernel<DIN, true><<<dim3((N + 63) / 64), b256, 0, stream>>>(
        bufS, W1, out, N);

    // ---- Layer 2
    agg_gather_kernel<DH><<<dim3((N + 3) / 4), b256, 0, stream>>>(
        rowptr, csr_src, csr_w, dinv, (const float4*)out, (float4*)bufS, N);
    gemm_nt_kernel<DH, true><<<dim3((N + 63) / 64), b256, 0, stream>>>(
        bufS, W2, out, N);

    // ---- Layer 3 (no relu)
    agg_gather_kernel<DH><<<dim3((N + 3) / 4), b256, 0, stream>>>(
        rowptr, csr_src, csr_w, dinv, (const float4*)out, (float4*)bufS, N);
    gemm_nt_kernel<DH, false><<<dim3((N + 63) / 64), b256, 0, stream>>>(
        bufS, W3, out, N);
}

// Round 4
// 1262.216 us; speedup vs baseline: 11.4991x; 1.2113x over previous
//
#include <hip/hip_runtime.h>

// ---------------------------------------------------------------------------
// GCN 3-layer forward on MI355X — Round 4: bf16 gather operands.
// R3 counters: agg_gather at 25 GB/s/CU = the per-CU vector-path ceiling
// (m13 streaming also ~25 GB/s/CU), VALUBusy 11% -> bytes-bound. So: store
// x/h1/h2 as bf16 (RNE), gather 512B rows instead of 1KB, accumulate fp32.
// bufS (agg output, GEMM A operand) and all GEMM math stay fp32.
// bf16 buffers live inside d_out (dead/overwritten safely); d_ws unchanged.
// Broadcast of (src,w) uses v_readlane (VALU) instead of ds_bpermute shfl.
// ---------------------------------------------------------------------------

constexpr int DIN = 128;
constexpr int DH  = 256;

__device__ __forceinline__ float bf2f(unsigned int u) {
    union { unsigned int i; float f; } c; c.i = u << 16; return c.f;
}
__device__ __forceinline__ unsigned short f2bf(float f) {
    union { float f; unsigned int i; } c; c.f = f;
    unsigned int i = c.i + 0x7FFFu + ((c.i >> 16) & 1u);   // round-nearest-even
    return (unsigned short)(i >> 16);
}

__global__ void zero_int_kernel(int* __restrict__ p, int n) {
    int i = blockIdx.x * blockDim.x + threadIdx.x;
    if (i < n) p[i] = 0;
}

__global__ void count_deg_kernel(const int* __restrict__ col, int E, int* __restrict__ deg) {
    int e = blockIdx.x * blockDim.x + threadIdx.x;
    if (e < E) atomicAdd(&deg[col[e]], 1);
}

// Single-block exclusive scan: deg[0..N) -> rowptr[0..N], rowptr[N] = E.
__global__ __launch_bounds__(1024) void scan_kernel(const int* __restrict__ deg,
                                                    int* __restrict__ rowptr, int N) {
    __shared__ int sums[1024];
    int t = threadIdx.x;
    int chunk = (N + 1023) / 1024;
    int s0 = t * chunk, s1 = min(N, s0 + chunk);
    int local = 0;
    for (int i = s0; i < s1; i++) local += deg[i];
    sums[t] = local;
    __syncthreads();
    for (int off = 1; off < 1024; off <<= 1) {
        int v = (t >= off) ? sums[t - off] : 0;
        __syncthreads();
        sums[t] += v;
        __syncthreads();
    }
    int prefix = (t == 0) ? 0 : sums[t - 1];
    for (int i = s0; i < s1; i++) { rowptr[i] = prefix; prefix += deg[i]; }
    if (t == 1023) rowptr[N] = sums[1023];
}

// dinv = 1/sqrt(deg+1); also zero deg for reuse as the CSR fill cursor.
__global__ void dinv_kernel(int* __restrict__ deg, float* __restrict__ dinv, int N) {
    int n = blockIdx.x * blockDim.x + threadIdx.x;
    if (n < N) {
        float d = (float)(deg[n] + 1);
        dinv[n] = 1.0f / sqrtf(d);
        deg[n] = 0;
    }
}

__global__ void fill_csr_kernel(const int* __restrict__ row, const int* __restrict__ col,
                                const int* __restrict__ rowptr, int* __restrict__ cnt,
                                const float* __restrict__ dinv,
                                int* __restrict__ csr_src, float* __restrict__ csr_w, int E) {
    int e = blockIdx.x * blockDim.x + threadIdx.x;
    if (e >= E) return;
    int r = row[e], c = col[e];
    int pos = rowptr[c] + atomicAdd(&cnt[c], 1);
    csr_src[pos] = r;
    csr_w[pos]   = dinv[r] * dinv[c];
}

// fp32 -> bf16 cast (RNE), 4 elems/thread.
__global__ void cast_bf16_kernel(const float4* __restrict__ in, ushort4* __restrict__ out, int n4) {
    int i = blockIdx.x * blockDim.x + threadIdx.x;
    if (i >= n4) return;
    float4 v = in[i];
    ushort4 o;
    o.x = f2bf(v.x); o.y = f2bf(v.y); o.z = f2bf(v.z); o.w = f2bf(v.w);
    out[i] = o;
}

// One L-lane group per node; lane handles 4 bf16 elems (8B load). L = D/4.
// in: bf16 rows [N][D]; out: fp32 rows [N][D]. Self-loop fused into init.
template<int D>
__global__ __launch_bounds__(256) void agg_gather_bf16_kernel(const int* __restrict__ rowptr,
                                                              const int* __restrict__ csr_src,
                                                              const float* __restrict__ csr_w,
                                                              const float* __restrict__ dinv,
                                                              const ushort4* __restrict__ in,
                                                              float4* __restrict__ out, int N) {
    constexpr int L = D / 4;                 // 64 (D=256) or 32 (D=128)
    constexpr int GPB = 256 / L;
    int n = blockIdx.x * GPB + threadIdx.x / L;
    if (n >= N) return;
    int lane = threadIdx.x % L;

    float di = dinv[n];
    float s = di * di;
    ushort4 sv = in[(size_t)n * L + lane];
    float4 acc = make_float4(bf2f(sv.x) * s, bf2f(sv.y) * s, bf2f(sv.z) * s, bf2f(sv.w) * s);

    int start = rowptr[n], end = rowptr[n + 1];
    for (int j0 = start; j0 < end; j0 += L) {
        int nb = end - j0; if (nb > L) nb = L;
        int   src = 0;
        float w   = 0.0f;
        if (lane < nb) { src = csr_src[j0 + lane]; w = csr_w[j0 + lane]; }
        if constexpr (L == 64) {
            // one node per wave: broadcast via v_readlane (uniform t, VALU-only)
            for (int t = 0; t < nb; ++t) {
                int   r  = __builtin_amdgcn_readlane(src, t);
                float ww = __int_as_float(__builtin_amdgcn_readlane(__float_as_int(w), t));
                ushort4 v = in[(size_t)r * L + lane];
                acc.x += ww * bf2f(v.x); acc.y += ww * bf2f(v.y);
                acc.z += ww * bf2f(v.z); acc.w += ww * bf2f(v.w);
            }
        } else {
            for (int t = 0; t < nb; ++t) {
                int   r  = __shfl(src, t, L);
                float ww = __shfl(w,   t, L);
                ushort4 v = in[(size_t)r * L + lane];
                acc.x += ww * bf2f(v.x); acc.y += ww * bf2f(v.y);
                acc.z += ww * bf2f(v.z); acc.w += ww * bf2f(v.w);
            }
        }
    }
    out[(size_t)n * L + lane] = acc;
}

// C[n][m] = sum_k A[n][k] * W[m][k];  A:[N,K] fp32 rm, W:[256,K] fp32 rm.
// 64x256 tile / block; OT = float (float4 store) or ushort (bf16 store).
template<int K, bool RELU, typename OT>
__global__ __launch_bounds__(256) void gemm_nt_kernel(const float* __restrict__ A,
                                                      const float* __restrict__ W,
                                                      OT* __restrict__ C, int N) {
    __shared__ __align__(16) float As[64][36];
    __shared__ __align__(16) float Ws[32][260];
    int tid = threadIdx.x;
    int tx = tid & 15, ty = tid >> 4;
    int m0 = blockIdx.x * 64;

    float4 acc[4][4];
    #pragma unroll
    for (int i = 0; i < 4; i++)
        #pragma unroll
        for (int j = 0; j < 4; j++) acc[i][j] = make_float4(0.f, 0.f, 0.f, 0.f);

    for (int k0 = 0; k0 < K; k0 += 32) {
        #pragma unroll
        for (int p = tid; p < 512; p += 256) {
            int rr = p >> 3, c4 = p & 7;
            int gr = m0 + rr;
            float4 va = make_float4(0.f, 0.f, 0.f, 0.f);
            if (gr < N) va = *(const float4*)(A + (size_t)gr * K + k0 + c4 * 4);
            *(float4*)&As[rr][c4 * 4] = va;
        }
        #pragma unroll
        for (int q = 0; q < 8; ++q) {
            int p = q * 256 + tid;
            int m = p >> 3, c4 = p & 7;
            float4 w = *(const float4*)(W + (size_t)m * K + k0 + c4 * 4);
            Ws[c4 * 4 + 0][m] = w.x;
            Ws[c4 * 4 + 1][m] = w.y;
            Ws[c4 * 4 + 2][m] = w.z;
            Ws[c4 * 4 + 3][m] = w.w;
        }
        __syncthreads();

        #pragma unroll 4
        for (int kk = 0; kk < 32; ++kk) {
            float a[4];
            #pragma unroll
            for (int i = 0; i < 4; i++) a[i] = As[ty * 4 + i][kk];
            float4 w[4];
            #pragma unroll
            for (int j = 0; j < 4; j++) w[j] = *(const float4*)&Ws[kk][tx * 4 + 64 * j];
            #pragma unroll
            for (int i = 0; i < 4; i++)
                #pragma unroll
                for (int j = 0; j < 4; j++) {
                    acc[i][j].x += a[i] * w[j].x;
                    acc[i][j].y += a[i] * w[j].y;
                    acc[i][j].z += a[i] * w[j].z;
                    acc[i][j].w += a[i] * w[j].w;
                }
        }
        __syncthreads();
    }

    #pragma unroll
    for (int i = 0; i < 4; i++) {
        int r = m0 + ty * 4 + i;
        if (r >= N) break;
        #pragma unroll
        for (int j = 0; j < 4; j++) {
            float4 v = acc[i][j];
            if (RELU) {
                v.x = fmaxf(v.x, 0.f); v.y = fmaxf(v.y, 0.f);
                v.z = fmaxf(v.z, 0.f); v.w = fmaxf(v.w, 0.f);
            }
            if constexpr (sizeof(OT) == 4) {
                *(float4*)((float*)C + (size_t)r * DH + tx * 4 + 64 * j) = v;
            } else {
                ushort4 o;
                o.x = f2bf(v.x); o.y = f2bf(v.y); o.z = f2bf(v.z); o.w = f2bf(v.w);
                *(ushort4*)((unsigned short*)C + (size_t)r * DH + tx * 4 + 64 * j) = o;
            }
        }
    }
}

extern "C" void kernel_launch(void* const* d_in, const int* in_sizes, int n_in,
                              void* d_out, int out_size, void* d_ws, size_t ws_size,
                              hipStream_t stream) {
    const float* x  = (const float*)d_in[0];
    const int*   ei = (const int*)d_in[1];
    const float* W1 = (const float*)d_in[2];
    const float* W2 = (const float*)d_in[3];
    const float* W3 = (const float*)d_in[4];
    float* out = (float*)d_out;

    int N = in_sizes[0] / DIN;
    int E = in_sizes[1] / 2;
    const int* row = ei;         // sources
    const int* col = ei + E;     // targets (aggregation)

    char* ws = (char*)d_ws;
    int*   deg     = (int*)ws;                      // N ints (later: fill cursor)
    float* dinv    = (float*)(ws + 400000);         // N floats
    int*   rowptr  = (int*)(ws + 800000);           // N+1 ints
    int*   csr_src = (int*)(ws + 1200016);          // E ints
    float* csr_w   = (float*)(ws + 7600016);        // E floats
    float* bufS    = (float*)(ws + 14000128);       // N*256 floats, fp32 agg out

    // bf16 staging lives inside d_out (N*256 fp32 = 102.4MB >= any of these):
    // xb (N*128 bf16, 25.6MB) is dead before GEMM1 writes h (N*256 bf16,
    // 51.2MB) over it; GEMM3 fully overwrites d_out with the fp32 result.
    unsigned short* hb = (unsigned short*)d_out;

    dim3 b256(256);

    // CSR build: deg -> rowptr -> dinv (+cursor reset) -> fill
    zero_int_kernel<<<dim3((N + 255) / 256), b256, 0, stream>>>(deg, N);
    count_deg_kernel<<<dim3((E + 255) / 256), b256, 0, stream>>>(col, E, deg);
    scan_kernel<<<dim3(1), dim3(1024), 0, stream>>>(deg, rowptr, N);
    dinv_kernel<<<dim3((N + 255) / 256), b256, 0, stream>>>(deg, dinv, N);
    fill_csr_kernel<<<dim3((E + 255) / 256), b256, 0, stream>>>(
        row, col, rowptr, deg, dinv, csr_src, csr_w, E);

    // ---- Layer 1: xb = bf16(x); s = A_n xb; h1 = bf16(relu(s @ W1^T))
    cast_bf16_kernel<<<dim3((N * (DIN / 4) + 255) / 256), b256, 0, stream>>>(
        (const float4*)x, (ushort4*)hb, N * (DIN / 4));
    agg_gather_bf16_kernel<DIN><<<dim3((N + 7) / 8), b256, 0, stream>>>(
        rowptr, csr_src, csr_w, dinv, (const ushort4*)hb, (float4*)bufS, N);
    gemm_nt_kernel<DIN, true, unsigned short><<<dim3((N + 63) / 64), b256, 0, stream>>>(
        bufS, W1, hb, N);

    // ---- Layer 2: s = A_n h1; h2 = bf16(relu(s @ W2^T))
    agg_gather_bf16_kernel<DH><<<dim3((N + 3) / 4), b256, 0, stream>>>(
        rowptr, csr_src, csr_w, dinv, (const ushort4*)hb, (float4*)bufS, N);
    gemm_nt_kernel<DH, true, unsigned short><<<dim3((N + 63) / 64), b256, 0, stream>>>(
        bufS, W2, hb, N);

    // ---- Layer 3: s = A_n h2; out = s @ W3^T (fp32, full overwrite of d_out)
    agg_gather_bf16_kernel<DH><<<dim3((N + 3) / 4), b256, 0, stream>>>(
        rowptr, csr_src, csr_w, dinv, (const ushort4*)hb, (float4*)bufS, N);
    gemm_nt_kernel<DH, false, float><<<dim3((N + 63) / 64), b256, 0, stream>>>(
        bufS, W3, out, N);
}